// Round 1
// baseline (501.194 us; speedup 1.0000x reference)
//
#include <hip/hip_runtime.h>

#define SSIM_H 512
#define SSIM_W 512
#define SSIM_PLANES 96
#define TILE_H 32
#define TILE_W 64
#define N_TOTAL 25165824.0

// 11-tap Gaussian, sigma=1.5, normalized (matches reference _gaussian_window).
__global__ __launch_bounds__(256, 2)
void ssim_l1_kernel(const float* __restrict__ pred,
                    const float* __restrict__ targ,
                    double* __restrict__ accum) {
  const float w[11] = {
      0.00102838f, 0.00759876f, 0.03600077f, 0.10936069f, 0.21300553f,
      0.26601172f, 0.21300553f, 0.10936069f, 0.03600077f, 0.00759876f,
      0.00102838f};

  // 5 horizontal-conv planes: x, y, x*x, y*y, x*y.  42 halo rows x 64 cols.
  __shared__ __align__(16) float hc[5][TILE_H + 10][TILE_W];
  __shared__ float red[2][4];

  const int tid  = (int)threadIdx.x;
  const int row0 = (int)blockIdx.y * TILE_H;
  const int col0 = (int)blockIdx.x * TILE_W;
  const size_t pbase = (size_t)blockIdx.z * (SSIM_H * SSIM_W);
  const float* __restrict__ xp = pred + pbase;
  const float* __restrict__ yp = targ + pbase;

  float l1 = 0.0f;

  // ---- Phase A: horizontal conv (rows -5..36 rel. tile), L1 on core rows ----
  // item = (halo row r in [0,42)) x (4-col chunk in [0,16))
  for (int item = tid; item < 42 * 16; item += 256) {
    const int r     = item >> 4;
    const int chunk = item & 15;
    const int irow  = row0 - 5 + r;
    const int cbase = col0 + chunk * 4;  // first core col of this chunk

    float av[14], bv[14];
    if (irow >= 0 && irow < SSIM_H) {
      const float* __restrict__ xr = xp + irow * SSIM_W;
      const float* __restrict__ yr = yp + irow * SSIM_W;
      if (cbase >= 5 && cbase <= SSIM_W - 9) {
#pragma unroll
        for (int j = 0; j < 14; ++j) {
          av[j] = xr[cbase - 5 + j];
          bv[j] = yr[cbase - 5 + j];
        }
      } else {
#pragma unroll
        for (int j = 0; j < 14; ++j) {
          const int c = cbase - 5 + j;
          const bool ok = (c >= 0) && (c < SSIM_W);
          av[j] = ok ? xr[c] : 0.0f;
          bv[j] = ok ? yr[c] : 0.0f;
        }
      }
    } else {
#pragma unroll
      for (int j = 0; j < 14; ++j) { av[j] = 0.0f; bv[j] = 0.0f; }
    }

    // L1 term: core rows only; window indices 5..8 are the 4 core columns.
    if (r >= 5 && r < 37) {
#pragma unroll
      for (int j = 5; j <= 8; ++j) l1 += fabsf(av[j] - bv[j]);
    }

    float hx[4]  = {0, 0, 0, 0}, hy[4]  = {0, 0, 0, 0};
    float hxx[4] = {0, 0, 0, 0}, hyy[4] = {0, 0, 0, 0}, hxy[4] = {0, 0, 0, 0};
#pragma unroll
    for (int j = 0; j < 14; ++j) {
      const float a = av[j], b = bv[j];
      const float aa = a * a, bb = b * b, ab = a * b;
#pragma unroll
      for (int o = 0; o < 4; ++o) {
        const int k = j - o;
        if (k >= 0 && k < 11) {
          hx[o]  += w[k] * a;
          hy[o]  += w[k] * b;
          hxx[o] += w[k] * aa;
          hyy[o] += w[k] * bb;
          hxy[o] += w[k] * ab;
        }
      }
    }
    const int cc = chunk * 4;
    *(float4*)&hc[0][r][cc] = make_float4(hx[0], hx[1], hx[2], hx[3]);
    *(float4*)&hc[1][r][cc] = make_float4(hy[0], hy[1], hy[2], hy[3]);
    *(float4*)&hc[2][r][cc] = make_float4(hxx[0], hxx[1], hxx[2], hxx[3]);
    *(float4*)&hc[3][r][cc] = make_float4(hyy[0], hyy[1], hyy[2], hyy[3]);
    *(float4*)&hc[4][r][cc] = make_float4(hxy[0], hxy[1], hxy[2], hxy[3]);
  }

  __syncthreads();

  // ---- Phase B: vertical conv + SSIM.  256 items = 16 col-groups x 16 2-row bands.
  float ssim_sum = 0.0f;
  {
    const int g = tid & 15;   // float4 col group
    const int b = tid >> 4;   // 2-row band
    float acc[5][2][4];
#pragma unroll
    for (int p = 0; p < 5; ++p)
#pragma unroll
      for (int rr = 0; rr < 2; ++rr)
#pragma unroll
        for (int q = 0; q < 4; ++q) acc[p][rr][q] = 0.0f;

#pragma unroll
    for (int j = 0; j < 12; ++j) {
#pragma unroll
      for (int p = 0; p < 5; ++p) {
        const float4 v = *(const float4*)&hc[p][2 * b + j][g * 4];
        const float vv[4] = {v.x, v.y, v.z, v.w};
#pragma unroll
        for (int q = 0; q < 4; ++q) {
          if (j < 11) acc[p][0][q] += w[j] * vv[q];
          if (j >= 1) acc[p][1][q] += w[j - 1] * vv[q];
        }
      }
    }

    const float C1v = 1.0e-4f, C2v = 9.0e-4f;
#pragma unroll
    for (int rr = 0; rr < 2; ++rr) {
#pragma unroll
      for (int q = 0; q < 4; ++q) {
        const float mu1 = acc[0][rr][q], mu2 = acc[1][rr][q];
        const float cxx = acc[2][rr][q], cyy = acc[3][rr][q], cxy = acc[4][rr][q];
        const float m11 = mu1 * mu1, m22 = mu2 * mu2, m12 = mu1 * mu2;
        const float num = (2.0f * m12 + C1v) * (2.0f * (cxy - m12) + C2v);
        const float den = (m11 + m22 + C1v) * ((cxx - m11) + (cyy - m22) + C2v);
        ssim_sum += num / den;
      }
    }
  }

  // ---- Reduction: wave shuffle -> LDS -> block -> global double atomics ----
  float v0 = l1, v1 = ssim_sum;
#pragma unroll
  for (int off = 32; off > 0; off >>= 1) {
    v0 += __shfl_down(v0, off, 64);
    v1 += __shfl_down(v1, off, 64);
  }
  const int lane = tid & 63, wid = tid >> 6;
  if (lane == 0) { red[0][wid] = v0; red[1][wid] = v1; }
  __syncthreads();
  if (tid == 0) {
    const double L = (double)red[0][0] + (double)red[0][1] +
                     (double)red[0][2] + (double)red[0][3];
    const double S = (double)red[1][0] + (double)red[1][1] +
                     (double)red[1][2] + (double)red[1][3];
    atomicAdd(accum + 0, L);
    atomicAdd(accum + 1, S);
  }
}

__global__ void finalize_kernel(const double* __restrict__ accum,
                                float* __restrict__ out) {
  const double invN = 1.0 / N_TOTAL;
  const double l1m = accum[0] * invN;
  const double sm  = accum[1] * invN;
  out[0] = (float)(0.84 * l1m + (1.0 - 0.84) * (1.0 - sm));
}

extern "C" void kernel_launch(void* const* d_in, const int* in_sizes, int n_in,
                              void* d_out, int out_size, void* d_ws, size_t ws_size,
                              hipStream_t stream) {
  const float* pred = (const float*)d_in[0];
  const float* targ = (const float*)d_in[1];
  float* out = (float*)d_out;
  double* accum = (double*)d_ws;

  hipMemsetAsync(d_ws, 0, 2 * sizeof(double), stream);

  dim3 grid(SSIM_W / TILE_W, SSIM_H / TILE_H, SSIM_PLANES);  // (8,16,96)
  ssim_l1_kernel<<<grid, 256, 0, stream>>>(pred, targ, accum);
  finalize_kernel<<<1, 1, 0, stream>>>(accum, out);
}